// Round 13
// baseline (201.455 us; speedup 1.0000x reference)
//
#include <hip/hip_runtime.h>
#include <hip/hip_bf16.h>

// SAGAN self-attention v17. B=8, C=64, N=4096, CQ=8.
// Algebraic refactor: out = Wv.(X.P^T)/d + bv  -- V never materialized.
//
// v16 failed to COMPILE (wrong K=16 builtin name + __has_builtin is false
// on the host pass -> broken fallback chosen). v17 keeps the insight but
// uses ONLY the K=32 builtin proven in all 12 rounds:
//   S^T C/D layout (row j=qd*4+r, col q=l16) IS a PV B-operand layout.
//   PV = mfma_f32_16x16x32_bf16 with ZERO-PADDED B:
//     pf = {pack(e0,e1), pack(e2,e3), 0, 0}  -> k=qd*8+i maps j=jb+qd*4+i
//          for i<4, zero for i>=4 (exact bf16 0.0 -> no NaN hazard).
//     A  = shufflevector(xf, xf) where xf = 8B bf16x4 load of
//          X[c][jb+qd*4..+3] (strictly in-bounds); high half multiplies
//          B=0 (finite x 0 = 0).
//   -> P never touches LDS. NO ds ops, NO barriers in the loop, no wave
//      coupling: pure register dataflow MFMA -> exp2 -> pack -> MFMA.
// Structure: grid B*(N/32)=1024 blocks (i-tile 32), 8 independent waves,
// wave w owns j in [w*512,+512), 32 steps x 16 j, all 64 channels.
// Regs: acc[4][2]=32 AGPR (->64 granule); arch live ~50-60 <= 64 cap.
// Tripwires: VGPR <= 64, WRITE_SIZE 8192 KB.
// Lessons kept: launch_bounds(512,4); masked qf / unmasked kf (v15);
// prep v12; epilogue = v16's tree reduce (vetted).

#define B_   8
#define C_   64
#define N_   4096
#define LOG2E 1.44269504088896340736f

typedef short bf16x8 __attribute__((ext_vector_type(8)));
typedef short bf16x4 __attribute__((ext_vector_type(4)));
typedef float f32x4  __attribute__((ext_vector_type(4)));
typedef unsigned int uint32;

#if __has_builtin(__builtin_amdgcn_exp2f)
#define EXP2(x) __builtin_amdgcn_exp2f(x)
#else
#define EXP2(x) __expf((x) * 0.69314718055994530942f)
#endif

__device__ __forceinline__ unsigned short f2bf_rn(float f) {
    union { __hip_bfloat16 h; unsigned short u; } cv;
    cv.h = __float2bfloat16(f);
    return cv.u;
}
__device__ __forceinline__ uint32 pk_rn(float lo, float hi) {
    return (uint32)f2bf_rn(lo) | ((uint32)f2bf_rn(hi) << 16);
}
// RTZ pack (1 v_perm): bias cancels in softmax ratio. Verified R2/R3.
__device__ __forceinline__ uint32 pack_rtz(float lo, float hi) {
    return __builtin_amdgcn_perm(__float_as_uint(hi), __float_as_uint(lo), 0x07060302);
}

// ---------------------------------------------------------------------------
// prep v12 (kept): Xb = bf16(x), Qh/Kh = projections (Q pre-scaled).
// Grid: B * N/64 = 512 blocks, 256 threads.
// ---------------------------------------------------------------------------
__global__ __launch_bounds__(256) void prep_kernel(
    const float* __restrict__ x,
    const float* __restrict__ wq, const float* __restrict__ bq,
    const float* __restrict__ wk, const float* __restrict__ bk,
    unsigned short* __restrict__ Qh, unsigned short* __restrict__ Kh,
    unsigned short* __restrict__ Xb)
{
    __shared__ float Xs[C_][64];
    __shared__ float Wqk[16][C_];
    __shared__ float Bqk[16];

    const int t  = threadIdx.x;
    const int b  = blockIdx.x >> 6;
    const int p0 = (blockIdx.x & 63) << 6;

    #pragma unroll
    for (int k = 0; k < 4; ++k) {
        int i = t + k * 256;
        int o = i >> 6;
        Wqk[o][i & 63] = (o < 8) ? wq[i] * LOG2E : wk[i - 512];
    }
    if (t < 16) Bqk[t] = (t < 8) ? bq[t] * LOG2E : bk[t - 8];

    #pragma unroll
    for (int k = 0; k < 4; ++k) {
        int i = t + k * 256;                 // 1024 float4 total
        int c = i >> 4, p4 = (i & 15) << 2;
        const float4 v = *(const float4*)(x + ((size_t)b * C_ + c) * N_ + p0 + p4);
        *(float4*)&Xs[c][p4] = v;
        uint2 u;
        u.x = pk_rn(v.x, v.y);
        u.y = pk_rn(v.z, v.w);
        *(uint2*)(Xb + ((size_t)b * C_ + c) * N_ + p0 + p4) = u;
    }
    __syncthreads();

    const int pix = t & 63, grp = t >> 6;    // grp wave-uniform
    float a[4];
    #pragma unroll
    for (int r = 0; r < 4; ++r) a[r] = Bqk[grp * 4 + r];
    #pragma unroll
    for (int c = 0; c < C_; ++c) {
        float xv = Xs[c][pix];               // lanes consecutive: conflict-free
        #pragma unroll
        for (int r = 0; r < 4; ++r) a[r] += Wqk[grp * 4 + r][c] * xv;  // broadcast
    }
    uint2 u;
    u.x = pk_rn(a[0], a[1]);
    u.y = pk_rn(a[2], a[3]);
    unsigned short* dst = (grp & 2) ? Kh : Qh;
    *(uint2*)(dst + ((size_t)b * N_ + p0 + pix) * 8 + (grp & 1) * 4) = u;
}

// ---------------------------------------------------------------------------
// attn v17: grid B * N/32 = 1024 blocks, 512 threads (8 independent waves).
// Wave w: j in [w*512,+512), 32 steps x 16 j, all 64 channels, i-tile 32.
// ZERO LDS / ZERO barriers in the loop. Epilogue: tree reduce + Wv GEMM.
// ---------------------------------------------------------------------------
__global__ __launch_bounds__(512, 4) void attn_mfma15_kernel(
    const unsigned short* __restrict__ Qh,
    const unsigned short* __restrict__ Kh,
    const unsigned short* __restrict__ Xb,
    const float* __restrict__ wv, const float* __restrict__ bv,
    float* __restrict__ out)
{
    // LDS map (41984 B; epilogue only -- loop touches no LDS):
    //  [0,32K)    dump region (tree reduce rounds); later Wvs fp32 [64][64]
    //  [32K,40K)  Or fp32 [64][32]
    //  [40K,+1K)  Dn fp32 [8][32]
    __shared__ __align__(16) char smem[41984];

    const int t    = threadIdx.x;
    const int w    = t >> 6;
    const int lane = t & 63;
    const int l16  = lane & 15;
    const int qd   = lane >> 4;
    const int b    = blockIdx.x >> 7;
    const int i0   = (blockIdx.x & 127) << 5;

    const bf16x8 z8 = {};
    const f32x4  zf = {};

    // Q frags (p1 B-operand, B[k=ch][n=q], quads 1-3 ZERO: K-pad makes
    // unmasked kf garbage safe -- 0 * finite = 0 for k>=8)
    bf16x8 qf[2];
    #pragma unroll
    for (int qt = 0; qt < 2; ++qt) {
        qf[qt] = z8;
        if (qd == 0)
            qf[qt] = *(const bf16x8*)(Qh + ((size_t)b * N_ + i0 + qt * 16 + l16) * 8);
    }

    const unsigned short* Kp = Kh + ((size_t)b * N_ + w * 512) * 8;
    const unsigned short* Xp = Xb + (size_t)b * C_ * N_ + w * 512;

    f32x4 acc[4][2];   // [ct][qt]: O'(c=ct*16+qd*4+r, q=qt*16+l16)
    #pragma unroll
    for (int ct = 0; ct < 4; ++ct)
        #pragma unroll
        for (int qt = 0; qt < 2; ++qt) acc[ct][qt] = zf;
    float dsum[2] = {0.f, 0.f};

    // preload K rows 0..15 (UNMASKED, v15-proven: all lanes load row l16;
    // k>=8 products hit qf zeros)
    bf16x8 kf[2];
    kf[0] = *(const bf16x8*)(Kp + (size_t)l16 * 8);

    #pragma unroll 2
    for (int s = 0; s < 32; ++s) {
        const int cur = s & 1, nxt = cur ^ 1;
        const int jb = s * 16;

        // X A-frags for this step: lane holds X[c=ct*16+l16][jb+qd*4+i],
        // i=0..3 (8B load, 8B-aligned, strictly in-bounds: col <= 511).
        // Consumed in p2 -- latency hides under p1+exp2 and 4-wave TLP.
        bf16x4 xf[4];
        #pragma unroll
        for (int ct = 0; ct < 4; ++ct)
            xf[ct] = *(const bf16x4*)(Xp + (size_t)(ct * 16 + l16) * N_ + jb + qd * 4);

        // phase 1: S^T (16 j x 16 q) per qt; rows j=jb+qd*4+r, col q=l16
        f32x4 sf[2];
        #pragma unroll
        for (int qt = 0; qt < 2; ++qt)
            sf[qt] = __builtin_amdgcn_mfma_f32_16x16x32_bf16(kf[cur], qf[qt], zf, 0, 0, 0);

        // prefetch next step's K rows (no barrier anywhere)
        if (s < 31)
            kf[nxt] = *(const bf16x8*)(Kp + (size_t)(jb + 16 + l16) * 8);

        // exp2 -> dsum -> pack. Packed pair IS this lane's B-fragment:
        // B[k=qd*8+i][n=l16] = P[j=jb+qd*4+i][q] for i<4, exact 0 for i>=4.
        #pragma unroll
        for (int qt = 0; qt < 2; ++qt) {
            float e0 = EXP2(sf[qt][0]);
            float e1 = EXP2(sf[qt][1]);
            float e2 = EXP2(sf[qt][2]);
            float e3 = EXP2(sf[qt][3]);
            dsum[qt] += (e0 + e1) + (e2 + e3);
            union { uint4 u; bf16x8 v; } pf;
            pf.u.x = pack_rtz(e0, e1);
            pf.u.y = pack_rtz(e2, e3);
            pf.u.z = 0u;
            pf.u.w = 0u;
            // phase 2: O' += X . P^T over this 16-j chunk (zero-padded K=32).
            // A high half = xf duplicate (finite real X data) x B=0 -> 0.
            #pragma unroll
            for (int ct = 0; ct < 4; ++ct) {
                bf16x8 a8 = __builtin_shufflevector(xf[ct], xf[ct],
                                                    0, 1, 2, 3, 0, 1, 2, 3);
                acc[ct][qt] = __builtin_amdgcn_mfma_f32_16x16x32_bf16(a8, pf.v, acc[ct][qt], 0, 0, 0);
            }
        }
    }

    // ---- denominator: per-wave shfl reduce -> Dn[w][32] ----
    #pragma unroll
    for (int qt = 0; qt < 2; ++qt) {
        float v = dsum[qt];
        v += __shfl_xor(v, 16, 64);
        v += __shfl_xor(v, 32, 64);
        if (qd == 0) *(float*)(smem + 40960 + (w * 32 + qt * 16 + l16) * 4) = v;
    }

    // ---- cross-wave O' tree reduce (first LDS use in this kernel) ----
    if (w >= 4) {                                      // R1 dump [0,32K)
        char* rb = smem + (w - 4) * 8192;
        #pragma unroll
        for (int ct = 0; ct < 4; ++ct)
            #pragma unroll
            for (int qt = 0; qt < 2; ++qt)
                *(f32x4*)(rb + (ct * 2 + qt) * 1024 + lane * 16) = acc[ct][qt];
    }
    __syncthreads();                                   // E1
    if (w < 4) {
        const char* rb = smem + w * 8192;
        #pragma unroll
        for (int ct = 0; ct < 4; ++ct)
            #pragma unroll
            for (int qt = 0; qt < 2; ++qt)
                acc[ct][qt] += *(const f32x4*)(rb + (ct * 2 + qt) * 1024 + lane * 16);
    }
    __syncthreads();                                   // E2: R1 reads done
    if (w == 2 || w == 3) {                            // R2 dump [0,16K)
        char* rb = smem + (w - 2) * 8192;
        #pragma unroll
        for (int ct = 0; ct < 4; ++ct)
            #pragma unroll
            for (int qt = 0; qt < 2; ++qt)
                *(f32x4*)(rb + (ct * 2 + qt) * 1024 + lane * 16) = acc[ct][qt];
    }
    __syncthreads();                                   // E3
    if (w < 2) {
        const char* rb = smem + w * 8192;
        #pragma unroll
        for (int ct = 0; ct < 4; ++ct)
            #pragma unroll
            for (int qt = 0; qt < 2; ++qt)
                acc[ct][qt] += *(const f32x4*)(rb + (ct * 2 + qt) * 1024 + lane * 16);
    }
    __syncthreads();                                   // E4: R2 reads done
    if (w == 1) {                                      // R3 dump [0,8K)
        #pragma unroll
        for (int ct = 0; ct < 4; ++ct)
            #pragma unroll
            for (int qt = 0; qt < 2; ++qt)
                *(f32x4*)(smem + (ct * 2 + qt) * 1024 + lane * 16) = acc[ct][qt];
    }
    __syncthreads();                                   // E5
    if (w == 0) {                                      // final add + scatter
        #pragma unroll
        for (int ct = 0; ct < 4; ++ct)
            #pragma unroll
            for (int qt = 0; qt < 2; ++qt)
                acc[ct][qt] += *(const f32x4*)(smem + (ct * 2 + qt) * 1024 + lane * 16);
        float* Or = (float*)(smem + 32768);
        #pragma unroll
        for (int ct = 0; ct < 4; ++ct)
            #pragma unroll
            for (int qt = 0; qt < 2; ++qt)
                #pragma unroll
                for (int r = 0; r < 4; ++r)
                    Or[(ct * 16 + qd * 4 + r) * 32 + qt * 16 + l16] = acc[ct][qt][r];
    }
    __syncthreads();                                   // E6: [0,16K) free
    {   // stage Wv fp32 -> [0,16K)
        float* Wvs = (float*)smem;
        for (int i = t; i < 4096; i += 512) Wvs[i] = wv[i];
    }
    __syncthreads();                                   // E7

    // ---- epilogue: out = Wv.O'/d + bv, fp32, all 8 waves ----
    const int q = t & 31, grp = t >> 5;                // 16 grps x 4 c
    const float* Wvs = (const float*)smem;
    const float* Or  = (const float*)(smem + 32768);
    const float* Dn  = (const float*)(smem + 40960);
    float dtot = 0.f;
    #pragma unroll
    for (int r = 0; r < 8; ++r) dtot += Dn[r * 32 + q];
    const float inv = 1.0f / dtot;
    float o[4];
    #pragma unroll
    for (int r = 0; r < 4; ++r) o[r] = 0.f;
    for (int k = 0; k < 64; ++k) {
        float ov = Or[k * 32 + q];                      // lanes consecutive q
        #pragma unroll
        for (int r = 0; r < 4; ++r)
            o[r] += Wvs[(grp * 4 + r) * 64 + k] * ov;   // uniform per half-wave
    }
    #pragma unroll
    for (int r = 0; r < 4; ++r)
        out[((size_t)b * C_ + grp * 4 + r) * N_ + i0 + q] = o[r] * inv + bv[grp * 4 + r];
}

// ---------------------------------------------------------------------------
// Fallback (workspace too small): round-1 fused fp32 flash kernel (verified).
// ---------------------------------------------------------------------------
__global__ __launch_bounds__(256) void attn_fused_fallback(
    const float* __restrict__ x,
    const float* __restrict__ wq, const float* __restrict__ bq,
    const float* __restrict__ wk, const float* __restrict__ bk,
    const float* __restrict__ wv, const float* __restrict__ bv,
    float* __restrict__ out)
{
    __shared__ float Qs[64][8];
    __shared__ float Ks[8][64];
    __shared__ float Vs[64][C_];
    __shared__ float Ws[64][64 + 1];
    __shared__ float Xs[C_ * 64];
    __shared__ float Wks[8][C_];
    __shared__ float Wvs[C_][C_ + 1];

    const int t     = threadIdx.x;
    const int b     = blockIdx.x / (N_ / 64);
    const int i0    = (blockIdx.x % (N_ / 64)) * 64;
    const int jlane = t & 63;
    const int wgrp  = t >> 6;

    for (int l = t; l < 8 * C_;  l += 256) Wks[l >> 6][l & 63] = wk[l];
    for (int l = t; l < C_ * C_; l += 256) Wvs[l >> 6][l & 63] = wv[l];
    for (int l = t; l < C_ * 64; l += 256)
        Xs[(l >> 6) * 64 + (l & 63)] = x[((size_t)b * C_ + (l >> 6)) * N_ + i0 + (l & 63)];
    __syncthreads();
    {
        int qi = jlane;
        #pragma unroll
        for (int r = 0; r < 2; ++r) {
            int cc = wgrp * 2 + r;
            float a = bq[cc];
            for (int c = 0; c < C_; ++c) a += wq[cc * C_ + c] * Xs[c * 64 + qi];
            Qs[qi][cc] = a;
        }
    }
    __syncthreads();

    const int qi2 = t >> 2;
    const int cb  = (t & 3) << 4;
    float accv[16];
    #pragma unroll
    for (int r = 0; r < 16; ++r) accv[r] = 0.f;
    float denom = 0.f;

    for (int j0 = 0; j0 < N_; j0 += 64) {
        for (int l = t; l < C_ * 64; l += 256)
            Xs[(l >> 6) * 64 + (l & 63)] = x[((size_t)b * C_ + (l >> 6)) * N_ + j0 + (l & 63)];
        __syncthreads();
        {
            int j = jlane;
            #pragma unroll
            for (int r = 0; r < 2; ++r) {
                int cc = wgrp * 2 + r;
                float a = bk[cc];
                for (int c = 0; c < C_; ++c) a += Wks[cc][c] * Xs[c * 64 + j];
                Ks[cc][j] = a;
            }
        }
        {
            int vc = jlane;
            #pragma unroll 2
            for (int r = 0; r < 16; ++r) {
                int j = wgrp * 16 + r;
                float a = bv[vc];
                for (int c = 0; c < C_; ++c) a += Wvs[vc][c] * Xs[c * 64 + j];
                Vs[j][vc] = a;
            }
        }
        __syncthreads();
        {
            float kreg[8];
            #pragma unroll
            for (int cc = 0; cc < 8; ++cc) kreg[cc] = Ks[cc][jlane];
            #pragma unroll 4
            for (int r = 0; r < 16; ++r) {
                int qi = wgrp * 16 + r;
                float e = 0.f;
                #pragma unroll
                for (int cc = 0; cc < 8; ++cc) e += Qs[qi][cc] * kreg[cc];
                Ws[qi][jlane] = __expf(e);
            }
        }
        __syncthreads();
        #pragma unroll 4
        for (int j = 0; j < 64; ++j) {
            float wv2 = Ws[qi2][j];
            denom += wv2;
            const float4* vrow = (const float4*)(&Vs[j][cb]);
            float4 v0 = vrow[0], v1 = vrow[1], v2 = vrow[2], v3 = vrow[3];
            accv[0]  += wv2 * v0.x; accv[1]  += wv2 * v0.y; accv[2]  += wv2 * v0.z; accv[3]  += wv2 * v0.w;
            accv[4]  += wv2 * v1.x; accv[5]  += wv2 * v1.y; accv[6]  += wv2 * v1.z; accv[7]  += wv2 * v1.w;
            accv[8]  += wv2 * v2.x; accv[9]  += wv2 * v2.y; accv[10] += wv2 * v2.z; accv[11] += wv2 * v2.w;
            accv[12] += wv2 * v3.x; accv[13] += wv2 * v3.y; accv[14] += wv2 * v3.z; accv[15] += wv2 * v3.w;
        }
        __syncthreads();
    }

    const float inv = 1.0f / denom;
    #pragma unroll
    for (int r = 0; r < 16; ++r)
        out[((size_t)b * C_ + cb + r) * N_ + i0 + qi2] = accv[r] * inv;
}

// ---------------------------------------------------------------------------
extern "C" void kernel_launch(void* const* d_in, const int* in_sizes, int n_in,
                              void* d_out, int out_size, void* d_ws, size_t ws_size,
                              hipStream_t stream)
{
    const float* x  = (const float*)d_in[0];
    const float* wq = (const float*)d_in[1];
    const float* bq = (const float*)d_in[2];
    const float* wk = (const float*)d_in[3];
    const float* bk = (const float*)d_in[4];
    const float* wv = (const float*)d_in[5];
    const float* bv = (const float*)d_in[6];
    float* out = (float*)d_out;

    const size_t nQ = (size_t)B_ * N_ * 8;        // 256K elems
    const size_t nX = (size_t)B_ * C_ * N_;       // 2M elems
    const size_t needed = (2 * nQ + nX) * sizeof(unsigned short);   // 5 MB

    if (ws_size >= needed) {
        unsigned short* Qh = (unsigned short*)d_ws;
        unsigned short* Kh = Qh + nQ;
        unsigned short* Xb = Kh + nQ;
        prep_kernel<<<B_ * (N_ / 64), 256, 0, stream>>>(x, wq, bq, wk, bk, Qh, Kh, Xb);
        attn_mfma15_kernel<<<B_ * (N_ / 32), 512, 0, stream>>>(Qh, Kh, Xb, wv, bv, out);
    } else {
        attn_fused_fallback<<<B_ * (N_ / 64), 256, 0, stream>>>(x, wq, bq, wk, bk, wv, bv, out);
    }
}

// Round 14
// 147.138 us; speedup vs baseline: 1.3692x; 1.3692x over previous
//
#include <hip/hip_runtime.h>
#include <hip/hip_bf16.h>

// SAGAN self-attention v18. B=8, C=64, N=4096, CQ=8.
// Algebraic refactor: out = Wv.(X.P^T)/d + bv  -- V never materialized.
//
// v17 verdict: conflicts 8.45M->65K yet 2.7x SLOWER -> LDS round-trip was
// never the wall; v17 died of doubled p2 MFMAs + half-utilized 8B X loads
// + fully-serial per-wave chain. Last untested lever: the loop barrier
// couples 8 waves though data flows only pair-wise.
//
// v18 = SOLO-WAVE P round-trip, ZERO barriers in the loop:
//   wave computes BOTH jt halves (4 p1 MFMA/step) and all 64 channels
//   (8 p2 MFMA/step, full K=32 -- no zero-pad), qt=2 (i-tile 32) so
//   acc[4][2]=32 AGPR. P buffer is WAVE-PRIVATE (8 x 4KB dbuf): the
//   write->read hazard is same-wave, ordered by compiler-inserted
//   lgkmcnt -- no s_barrier, no coupling, waves fully desync.
//   Chip-wide MFMA/exp2 totals identical to v15; X L2 traffic 2x
//   (i-tile 32 halves reuse) ~ +8us L2, accepted.
// Registers match v10's proven-64 class: qf 8 + kf dbuf 16 + xf in-step
// 16 + misc ~12 (+ sf 16 transient); acc 32 AGPR. launch_bounds(512,4).
// Tripwires: VGPR <= 64, WRITE_SIZE 8192 KB (spill = abort direction).
// Epilogue: v17's tree reduce VERBATIM (numerically vetted, passing).
// prep v12 kept.

#define B_   8
#define C_   64
#define N_   4096
#define LOG2E 1.44269504088896340736f

typedef short bf16x8 __attribute__((ext_vector_type(8)));
typedef float f32x4  __attribute__((ext_vector_type(4)));
typedef unsigned int uint32;

#if __has_builtin(__builtin_amdgcn_exp2f)
#define EXP2(x) __builtin_amdgcn_exp2f(x)
#else
#define EXP2(x) __expf((x) * 0.69314718055994530942f)
#endif

__device__ __forceinline__ unsigned short f2bf_rn(float f) {
    union { __hip_bfloat16 h; unsigned short u; } cv;
    cv.h = __float2bfloat16(f);
    return cv.u;
}
__device__ __forceinline__ uint32 pk_rn(float lo, float hi) {
    return (uint32)f2bf_rn(lo) | ((uint32)f2bf_rn(hi) << 16);
}
// RTZ pack (1 v_perm): bias cancels in softmax ratio. Verified R2/R3.
__device__ __forceinline__ uint32 pack_rtz(float lo, float hi) {
    return __builtin_amdgcn_perm(__float_as_uint(hi), __float_as_uint(lo), 0x07060302);
}

// ---------------------------------------------------------------------------
// prep v12 (kept): Xb = bf16(x), Qh/Kh = projections (Q pre-scaled).
// Grid: B * N/64 = 512 blocks, 256 threads.
// ---------------------------------------------------------------------------
__global__ __launch_bounds__(256) void prep_kernel(
    const float* __restrict__ x,
    const float* __restrict__ wq, const float* __restrict__ bq,
    const float* __restrict__ wk, const float* __restrict__ bk,
    unsigned short* __restrict__ Qh, unsigned short* __restrict__ Kh,
    unsigned short* __restrict__ Xb)
{
    __shared__ float Xs[C_][64];
    __shared__ float Wqk[16][C_];
    __shared__ float Bqk[16];

    const int t  = threadIdx.x;
    const int b  = blockIdx.x >> 6;
    const int p0 = (blockIdx.x & 63) << 6;

    #pragma unroll
    for (int k = 0; k < 4; ++k) {
        int i = t + k * 256;
        int o = i >> 6;
        Wqk[o][i & 63] = (o < 8) ? wq[i] * LOG2E : wk[i - 512];
    }
    if (t < 16) Bqk[t] = (t < 8) ? bq[t] * LOG2E : bk[t - 8];

    #pragma unroll
    for (int k = 0; k < 4; ++k) {
        int i = t + k * 256;                 // 1024 float4 total
        int c = i >> 4, p4 = (i & 15) << 2;
        const float4 v = *(const float4*)(x + ((size_t)b * C_ + c) * N_ + p0 + p4);
        *(float4*)&Xs[c][p4] = v;
        uint2 u;
        u.x = pk_rn(v.x, v.y);
        u.y = pk_rn(v.z, v.w);
        *(uint2*)(Xb + ((size_t)b * C_ + c) * N_ + p0 + p4) = u;
    }
    __syncthreads();

    const int pix = t & 63, grp = t >> 6;    // grp wave-uniform
    float a[4];
    #pragma unroll
    for (int r = 0; r < 4; ++r) a[r] = Bqk[grp * 4 + r];
    #pragma unroll
    for (int c = 0; c < C_; ++c) {
        float xv = Xs[c][pix];               // lanes consecutive: conflict-free
        #pragma unroll
        for (int r = 0; r < 4; ++r) a[r] += Wqk[grp * 4 + r][c] * xv;  // broadcast
    }
    uint2 u;
    u.x = pk_rn(a[0], a[1]);
    u.y = pk_rn(a[2], a[3]);
    unsigned short* dst = (grp & 2) ? Kh : Qh;
    *(uint2*)(dst + ((size_t)b * N_ + p0 + pix) * 8 + (grp & 1) * 4) = u;
}

// ---------------------------------------------------------------------------
// attn v18: grid B * N/32 = 1024 blocks, 512 threads (8 independent waves).
// Wave w: j in [w*512,+512), 16 steps x 32 j (both jt halves), all 64
// channels, i-tile 32 (qt=2). Wave-PRIVATE P dbuf -> zero loop barriers.
// ---------------------------------------------------------------------------
__global__ __launch_bounds__(512, 4) void attn_mfma16_kernel(
    const unsigned short* __restrict__ Qh,
    const unsigned short* __restrict__ Kh,
    const unsigned short* __restrict__ Xb,
    const float* __restrict__ wv, const float* __restrict__ bv,
    float* __restrict__ out)
{
    // LDS map (41984 B):
    //  loop:   [0,32K)   P: wave w at w*4096, dbuf +cur*2048, qt*1024 +
    //                    l16*64 + XOR-swz offs (v4-proven layout, qt=2)
    //  epilog: [0,32K)   reuse: tree-reduce dump slots; then Wvs [0,16K)
    //          [32K,40K) Or fp32 [64][32]
    //          [40K,+1K) Dn fp32 [8][32]
    __shared__ __align__(16) char smem[41984];

    const int t    = threadIdx.x;
    const int w    = t >> 6;
    const int lane = t & 63;
    const int l16  = lane & 15;
    const int qd   = lane >> 4;
    const int b    = blockIdx.x >> 7;
    const int i0   = (blockIdx.x & 127) << 5;

    const bf16x8 z8 = {};
    const f32x4  zf = {};

    // Q frags (p1 B-operand, B[k=ch][n=q], quads 1-3 ZERO: K-pad makes
    // unmasked kf safe -- 0 * finite = 0 for k>=8)
    bf16x8 qf[2];
    #pragma unroll
    for (int qt = 0; qt < 2; ++qt) {
        qf[qt] = z8;
        if (qd == 0)
            qf[qt] = *(const bf16x8*)(Qh + ((size_t)b * N_ + i0 + qt * 16 + l16) * 8);
    }

    const unsigned short* Kp = Kh + ((size_t)b * N_ + w * 512) * 8;
    const unsigned short* Xp = Xb + (size_t)b * C_ * N_ + w * 512;

    f32x4 acc[4][2];   // [ct][qt]: O'(c=ct*16+qd*4+r, q=qt*16+l16)
    #pragma unroll
    for (int ct = 0; ct < 4; ++ct)
        #pragma unroll
        for (int qt = 0; qt < 2; ++qt) acc[ct][qt] = zf;
    float dsum[2] = {0.f, 0.f};

    // wave-private P addressing (v4-proven XOR swizzle, conflict-optimal)
    const int swz   = (l16 & 3) << 2;
    const int pbase = w * 4096 + l16 * 64;      // + cur*2048 + qt*1024
    int woff[2];
    #pragma unroll
    for (int jt = 0; jt < 2; ++jt) woff[jt] = ((jt * 8 + qd * 2) ^ swz) << 2;
    const int roff = ((qd * 4) ^ swz) << 2;

    // kf double-buffer (prefetched); xf loaded in-step (consumed late).
    bf16x8 kf[2][2];
    #pragma unroll
    for (int jt = 0; jt < 2; ++jt)
        kf[0][jt] = *(const bf16x8*)(Kp + (size_t)(jt * 16 + l16) * 8);  // unmasked

    #pragma unroll 2
    for (int s = 0; s < 16; ++s) {
        const int cur = s & 1, nxt = cur ^ 1;
        const int jb = s * 32;
        char* pb_ = smem + pbase + cur * 2048;

        // X frags for this step (16B fully-coalesced: qd*16B contiguous
        // per row, 16 rows -> 16 lines 100% used). Consumed in p2 --
        // latency hides under p1 + exp2 + wave desync TLP.
        bf16x8 xf[4];
        #pragma unroll
        for (int ct = 0; ct < 4; ++ct)
            xf[ct] = *(const bf16x8*)(Xp + (size_t)(ct * 16 + l16) * N_ + jb + qd * 8);

        // phase 1: S^T both jt halves (rows j=jb+jt*16+qd*4+r, col q=l16)
        f32x4 sf[2][2];
        #pragma unroll
        for (int jt = 0; jt < 2; ++jt)
            #pragma unroll
            for (int qt = 0; qt < 2; ++qt)
                sf[jt][qt] = __builtin_amdgcn_mfma_f32_16x16x32_bf16(kf[cur][jt], qf[qt], zf, 0, 0, 0);

        // prefetch next step's K rows (unmasked)
        if (s < 15) {
            #pragma unroll
            for (int jt = 0; jt < 2; ++jt)
                kf[nxt][jt] = *(const bf16x8*)(Kp + (size_t)(jb + 32 + jt * 16 + l16) * 8);
        }

        // exp2 -> dsum -> pack into the WAVE-PRIVATE buffer. Same-wave
        // write->read ordering via compiler lgkmcnt; dbuf makes next
        // step's overwrite safe. NO barrier.
        #pragma unroll
        for (int jt = 0; jt < 2; ++jt)
            #pragma unroll
            for (int qt = 0; qt < 2; ++qt) {
                float e0 = EXP2(sf[jt][qt][0]);
                float e1 = EXP2(sf[jt][qt][1]);
                float e2 = EXP2(sf[jt][qt][2]);
                float e3 = EXP2(sf[jt][qt][3]);
                dsum[qt] += (e0 + e1) + (e2 + e3);
                uint2 u;
                u.x = pack_rtz(e0, e1);
                u.y = pack_rtz(e2, e3);
                *(uint2*)(pb_ + qt * 1024 + woff[jt]) = u;
            }

        // phase 2: O' += X . P^T over the full 32-j step (K=32, no pad)
        #pragma unroll
        for (int qt = 0; qt < 2; ++qt) {
            bf16x8 pbf = *(const bf16x8*)(pb_ + qt * 1024 + roff);
            #pragma unroll
            for (int ct = 0; ct < 4; ++ct)
                acc[ct][qt] = __builtin_amdgcn_mfma_f32_16x16x32_bf16(xf[ct], pbf, acc[ct][qt], 0, 0, 0);
        }
    }

    // ---- denominator: per-wave shfl reduce -> Dn[w][32] ----
    #pragma unroll
    for (int qt = 0; qt < 2; ++qt) {
        float v = dsum[qt];
        v += __shfl_xor(v, 16, 64);
        v += __shfl_xor(v, 32, 64);
        if (qd == 0) *(float*)(smem + 40960 + (w * 32 + qt * 16 + l16) * 4) = v;
    }

    // ---- cross-wave O' tree reduce (v17's vetted epilogue) ----
    __syncthreads();                                   // E0: loop LDS done
    if (w >= 4) {                                      // R1 dump [0,32K)
        char* rb = smem + (w - 4) * 8192;
        #pragma unroll
        for (int ct = 0; ct < 4; ++ct)
            #pragma unroll
            for (int qt = 0; qt < 2; ++qt)
                *(f32x4*)(rb + (ct * 2 + qt) * 1024 + lane * 16) = acc[ct][qt];
    }
    __syncthreads();                                   // E1
    if (w < 4) {
        const char* rb = smem + w * 8192;
        #pragma unroll
        for (int ct = 0; ct < 4; ++ct)
            #pragma unroll
            for (int qt = 0; qt < 2; ++qt)
                acc[ct][qt] += *(const f32x4*)(rb + (ct * 2 + qt) * 1024 + lane * 16);
    }
    __syncthreads();                                   // E2: R1 reads done
    if (w == 2 || w == 3) {                            // R2 dump [0,16K)
        char* rb = smem + (w - 2) * 8192;
        #pragma unroll
        for (int ct = 0; ct < 4; ++ct)
            #pragma unroll
            for (int qt = 0; qt < 2; ++qt)
                *(f32x4*)(rb + (ct * 2 + qt) * 1024 + lane * 16) = acc[ct][qt];
    }
    __syncthreads();                                   // E3
    if (w < 2) {
        const char* rb = smem + w * 8192;
        #pragma unroll
        for (int ct = 0; ct < 4; ++ct)
            #pragma unroll
            for (int qt = 0; qt < 2; ++qt)
                acc[ct][qt] += *(const f32x4*)(rb + (ct * 2 + qt) * 1024 + lane * 16);
    }
    __syncthreads();                                   // E4: R2 reads done
    if (w == 1) {                                      // R3 dump [0,8K)
        #pragma unroll
        for (int ct = 0; ct < 4; ++ct)
            #pragma unroll
            for (int qt = 0; qt < 2; ++qt)
                *(f32x4*)(smem + (ct * 2 + qt) * 1024 + lane * 16) = acc[ct][qt];
    }
    __syncthreads();                                   // E5
    if (w == 0) {                                      // final add + scatter
        #pragma unroll
        for (int ct = 0; ct < 4; ++ct)
            #pragma unroll
            for (int qt = 0; qt < 2; ++qt)
                acc[ct][qt] += *(const f32x4*)(smem + (ct * 2 + qt) * 1024 + lane * 16);
        float* Or = (float*)(smem + 32768);
        #pragma unroll
        for (int ct = 0; ct < 4; ++ct)
            #pragma unroll
            for (int qt = 0; qt < 2; ++qt)
                #pragma unroll
                for (int r = 0; r < 4; ++r)
                    Or[(ct * 16 + qd * 4 + r) * 32 + qt * 16 + l16] = acc[ct][qt][r];
    }
    __syncthreads();                                   // E6: [0,16K) free
    {   // stage Wv fp32 -> [0,16K)
        float* Wvs = (float*)smem;
        for (int i = t; i < 4096; i += 512) Wvs[i] = wv[i];
    }
    __syncthreads();                                   // E7

    // ---- epilogue: out = Wv.O'/d + bv, fp32, all 8 waves ----
    const int q = t & 31, grp = t >> 5;                // 16 grps x 4 c
    const float* Wvs = (const float*)smem;
    const float* Or  = (const float*)(smem + 32768);
    const float* Dn  = (const float*)(smem + 40960);
    float dtot = 0.f;
    #pragma unroll
    for (int r = 0; r < 8; ++r) dtot += Dn[r * 32 + q];
    const float inv = 1.0f / dtot;
    float o[4];
    #pragma unroll
    for (int r = 0; r < 4; ++r) o[r] = 0.f;
    for (int k = 0; k < 64; ++k) {
        float ov = Or[k * 32 + q];                      // lanes consecutive q
        #pragma unroll
        for (int r = 0; r < 4; ++r)
            o[r] += Wvs[(grp * 4 + r) * 64 + k] * ov;
    }
    #pragma unroll
    for (int r = 0; r < 4; ++r)
        out[((size_t)b * C_ + grp * 4 + r) * N_ + i0 + q] = o[r] * inv + bv[grp * 4 + r];
}

// ---------------------------------------------------------------------------
// Fallback (workspace too small): round-1 fused fp32 flash kernel (verified).
// ---------------------------------------------------------------------------
__global__ __launch_bounds__(256) void attn_fused_fallback(
    const float* __restrict__ x,
    const float* __restrict__ wq, const float* __restrict__ bq,
    const float* __restrict__ wk, const float* __restrict__ bk,
    const float* __restrict__ wv, const float* __restrict__ bv,
    float* __restrict__ out)
{
    __shared__ float Qs[64][8];
    __shared__ float Ks[8][64];
    __shared__ float Vs[64][C_];
    __shared__ float Ws[64][64 + 1];
    __shared__ float Xs[C_ * 64];
    __shared__ float Wks[8][C_];
    __shared__ float Wvs[C_][C_ + 1];

    const int t     = threadIdx.x;
    const int b     = blockIdx.x / (N_ / 64);
    const int i0    = (blockIdx.x % (N_ / 64)) * 64;
    const int jlane = t & 63;
    const int wgrp  = t >> 6;

    for (int l = t; l < 8 * C_;  l += 256) Wks[l >> 6][l & 63] = wk[l];
    for (int l = t; l < C_ * C_; l += 256) Wvs[l >> 6][l & 63] = wv[l];
    for (int l = t; l < C_ * 64; l += 256)
        Xs[(l >> 6) * 64 + (l & 63)] = x[((size_t)b * C_ + (l >> 6)) * N_ + i0 + (l & 63)];
    __syncthreads();
    {
        int qi = jlane;
        #pragma unroll
        for (int r = 0; r < 2; ++r) {
            int cc = wgrp * 2 + r;
            float a = bq[cc];
            for (int c = 0; c < C_; ++c) a += wq[cc * C_ + c] * Xs[c * 64 + qi];
            Qs[qi][cc] = a;
        }
    }
    __syncthreads();

    const int qi2 = t >> 2;
    const int cb  = (t & 3) << 4;
    float accv[16];
    #pragma unroll
    for (int r = 0; r < 16; ++r) accv[r] = 0.f;
    float denom = 0.f;

    for (int j0 = 0; j0 < N_; j0 += 64) {
        for (int l = t; l < C_ * 64; l += 256)
            Xs[(l >> 6) * 64 + (l & 63)] = x[((size_t)b * C_ + (l >> 6)) * N_ + j0 + (l & 63)];
        __syncthreads();
        {
            int j = jlane;
            #pragma unroll
            for (int r = 0; r < 2; ++r) {
                int cc = wgrp * 2 + r;
                float a = bk[cc];
                for (int c = 0; c < C_; ++c) a += Wks[cc][c] * Xs[c * 64 + j];
                Ks[cc][j] = a;
            }
        }
        {
            int vc = jlane;
            #pragma unroll 2
            for (int r = 0; r < 16; ++r) {
                int j = wgrp * 16 + r;
                float a = bv[vc];
                for (int c = 0; c < C_; ++c) a += Wvs[vc][c] * Xs[c * 64 + j];
                Vs[j][vc] = a;
            }
        }
        __syncthreads();
        {
            float kreg[8];
            #pragma unroll
            for (int cc = 0; cc < 8; ++cc) kreg[cc] = Ks[cc][jlane];
            #pragma unroll 4
            for (int r = 0; r < 16; ++r) {
                int qi = wgrp * 16 + r;
                float e = 0.f;
                #pragma unroll
                for (int cc = 0; cc < 8; ++cc) e += Qs[qi][cc] * kreg[cc];
                Ws[qi][jlane] = __expf(e);
            }
        }
        __syncthreads();
        #pragma unroll 4
        for (int j = 0; j < 64; ++j) {
            float wv2 = Ws[qi2][j];
            denom += wv2;
            const float4* vrow = (const float4*)(&Vs[j][cb]);
            float4 v0 = vrow[0], v1 = vrow[1], v2 = vrow[2], v3 = vrow[3];
            accv[0]  += wv2 * v0.x; accv[1]  += wv2 * v0.y; accv[2]  += wv2 * v0.z; accv[3]  += wv2 * v0.w;
            accv[4]  += wv2 * v1.x; accv[5]  += wv2 * v1.y; accv[6]  += wv2 * v1.z; accv[7]  += wv2 * v1.w;
            accv[8]  += wv2 * v2.x; accv[9]  += wv2 * v2.y; accv[10] += wv2 * v2.z; accv[11] += wv2 * v2.w;
            accv[12] += wv2 * v3.x; accv[13] += wv2 * v3.y; accv[14] += wv2 * v3.z; accv[15] += wv2 * v3.w;
        }
        __syncthreads();
    }

    const float inv = 1.0f / denom;
    #pragma unroll
    for (int r = 0; r < 16; ++r)
        out[((size_t)b * C_ + cb + r) * N_ + i0 + qi2] = accv[r] * inv;
}

// ---------------------------------------------------------------------------
extern "C" void kernel_launch(void* const* d_in, const int* in_sizes, int n_in,
                              void* d_out, int out_size, void* d_ws, size_t ws_size,
                              hipStream_t stream)
{
    const float* x  = (const float*)d_in[0];
    const float* wq = (const float*)d_in[1];
    const float* bq = (const float*)d_in[2];
    const float* wk = (const float*)d_in[3];
    const float* bk = (const float*)d_in[4];
    const float* wv = (const float*)d_in[5];
    const float* bv = (const float*)d_in[6];
    float* out = (float*)d_out;

    const size_t nQ = (size_t)B_ * N_ * 8;        // 256K elems
    const size_t nX = (size_t)B_ * C_ * N_;       // 2M elems
    const size_t needed = (2 * nQ + nX) * sizeof(unsigned short);   // 5 MB

    if (ws_size >= needed) {
        unsigned short* Qh = (unsigned short*)d_ws;
        unsigned short* Kh = Qh + nQ;
        unsigned short* Xb = Kh + nQ;
        prep_kernel<<<B_ * (N_ / 64), 256, 0, stream>>>(x, wq, bq, wk, bk, Qh, Kh, Xb);
        attn_mfma16_kernel<<<B_ * (N_ / 32), 512, 0, stream>>>(Qh, Kh, Xb, wv, bv, out);
    } else {
        attn_fused_fallback<<<B_ * (N_ / 64), 256, 0, stream>>>(x, wq, bq, wk, bk, wv, bv, out);
    }
}

// Round 15
// 118.614 us; speedup vs baseline: 1.6984x; 1.2405x over previous
//
#include <hip/hip_runtime.h>
#include <hip/hip_bf16.h>

// SAGAN self-attention v19. B=8, C=64, N=4096, CQ=8.
// Algebraic refactor: out = Wv.(X.P^T)/d + bv  -- V never materialized.
//
// v17/v18 verdicts: removing LDS (v17, 2.7x slower) or barriers (v18,
// 1.6x slower) both REGRESS -> v15's pair-coupled structure is optimal
// among tested; its coupling overlaps each wave's serial chain with its
// partner's. v19 = v15 (best: 51.0us attn / 118.78 dur) + two
// zero-register tweaks never cleanly tested in THIS structure:
//   (1) balanced ones-MFMA: h==0 does qt{0,1}, h==1 does qt{2,3}
//       (v15 put all 4 on h==0 -> per-step imbalance paid at the
//       barrier). Dn writes disjoint columns; epilogue unchanged.
//   (2) s_setprio(1) around the p2 MFMA cluster: 4 waves/SIMD come from
//       2 independent desynced blocks -> T5 role diversity exists
//       (unlike v7's confounded test).
// Tripwires: VGPR_Count 64, WRITE_SIZE 8192 KB. Regression -> revert to
// v15 verbatim next round.

#define B_   8
#define C_   64
#define N_   4096
#define LOG2E 1.44269504088896340736f

typedef short bf16x8 __attribute__((ext_vector_type(8)));
typedef float f32x4  __attribute__((ext_vector_type(4)));
typedef unsigned int uint32;

#if __has_builtin(__builtin_amdgcn_exp2f)
#define EXP2(x) __builtin_amdgcn_exp2f(x)
#else
#define EXP2(x) __expf((x) * 0.69314718055994530942f)
#endif

__device__ __forceinline__ unsigned short f2bf_rn(float f) {
    union { __hip_bfloat16 h; unsigned short u; } cv;
    cv.h = __float2bfloat16(f);
    return cv.u;
}
__device__ __forceinline__ uint32 pk_rn(float lo, float hi) {
    return (uint32)f2bf_rn(lo) | ((uint32)f2bf_rn(hi) << 16);
}
// RTZ pack (1 v_perm): bias cancels in softmax ratio. Verified R2/R3.
__device__ __forceinline__ uint32 pack_rtz(float lo, float hi) {
    return __builtin_amdgcn_perm(__float_as_uint(hi), __float_as_uint(lo), 0x07060302);
}

// ---------------------------------------------------------------------------
// prep v12 (kept): Xb = bf16(x), Qh/Kh = projections (Q pre-scaled).
// Grid: B * N/64 = 512 blocks, 256 threads.
// ---------------------------------------------------------------------------
__global__ __launch_bounds__(256) void prep_kernel(
    const float* __restrict__ x,
    const float* __restrict__ wq, const float* __restrict__ bq,
    const float* __restrict__ wk, const float* __restrict__ bk,
    unsigned short* __restrict__ Qh, unsigned short* __restrict__ Kh,
    unsigned short* __restrict__ Xb)
{
    __shared__ float Xs[C_][64];
    __shared__ float Wqk[16][C_];
    __shared__ float Bqk[16];

    const int t  = threadIdx.x;
    const int b  = blockIdx.x >> 6;
    const int p0 = (blockIdx.x & 63) << 6;

    #pragma unroll
    for (int k = 0; k < 4; ++k) {
        int i = t + k * 256;
        int o = i >> 6;
        Wqk[o][i & 63] = (o < 8) ? wq[i] * LOG2E : wk[i - 512];
    }
    if (t < 16) Bqk[t] = (t < 8) ? bq[t] * LOG2E : bk[t - 8];

    #pragma unroll
    for (int k = 0; k < 4; ++k) {
        int i = t + k * 256;                 // 1024 float4 total
        int c = i >> 4, p4 = (i & 15) << 2;
        const float4 v = *(const float4*)(x + ((size_t)b * C_ + c) * N_ + p0 + p4);
        *(float4*)&Xs[c][p4] = v;
        uint2 u;
        u.x = pk_rn(v.x, v.y);
        u.y = pk_rn(v.z, v.w);
        *(uint2*)(Xb + ((size_t)b * C_ + c) * N_ + p0 + p4) = u;
    }
    __syncthreads();

    const int pix = t & 63, grp = t >> 6;    // grp wave-uniform
    float a[4];
    #pragma unroll
    for (int r = 0; r < 4; ++r) a[r] = Bqk[grp * 4 + r];
    #pragma unroll
    for (int c = 0; c < C_; ++c) {
        float xv = Xs[c][pix];               // lanes consecutive: conflict-free
        #pragma unroll
        for (int r = 0; r < 4; ++r) a[r] += Wqk[grp * 4 + r][c] * xv;  // broadcast
    }
    uint2 u;
    u.x = pk_rn(a[0], a[1]);
    u.y = pk_rn(a[2], a[3]);
    unsigned short* dst = (grp & 2) ? Kh : Qh;
    *(uint2*)(dst + ((size_t)b * N_ + p0 + pix) * 8 + (grp & 1) * 4) = u;
}

// ---------------------------------------------------------------------------
// attn v19: grid B * N/64 = 512 blocks, 512 threads (8 waves = 4 pairs).
// Pair p: j in [p*1024,+1024), 32 steps x 32 j. Wave h of pair: jt=h in
// phase 1, channel half h in phase 2. Loop barrier = lgkmcnt(0)+s_barrier.
// Balanced ones-MFMA denominator; setprio around p2 cluster.
// ---------------------------------------------------------------------------
__global__ __launch_bounds__(512, 4) void attn_mfma17_kernel(
    const unsigned short* __restrict__ Qh,
    const unsigned short* __restrict__ Kh,
    const unsigned short* __restrict__ Xb,
    const float* __restrict__ wv, const float* __restrict__ bv,
    float* __restrict__ out)
{
    // LDS map (67584 B; 2 blocks/CU):
    //  loop:   [0,32K)   P: pair p at p*8192, dbuf +cur*4096; inside:
    //                    qt*1024 + l16*64 + XOR-swz offs (conflict-optimal)
    //  epilog: [0,48K)   6 dump slots x 8KB; then [0,16K) Wvs after reads
    //          [48K,64K) Or fp32 [64][64]
    //          [64K,+1K) Dn [4][64] fp32 (pair p row; h splits columns)
    __shared__ __align__(16) char smem[67584];

    const int t    = threadIdx.x;
    const int w    = t >> 6;
    const int lane = t & 63;
    const int l16  = lane & 15;
    const int qd   = lane >> 4;
    const int p    = w & 3;     // pair -> j-slice
    const int h    = w >> 2;    // 0: jt0 + c[0,32) ; 1: jt1 + c[32,64)
    const int b    = blockIdx.x >> 6;
    const int i0   = (blockIdx.x & 63) << 6;

    const bf16x8 z8 = {};
    const f32x4  zf = {};
    const short ONE_BF = (short)0x3F80;              // bf16 1.0
    const bf16x8 ones = {ONE_BF, ONE_BF, ONE_BF, ONE_BF,
                         ONE_BF, ONE_BF, ONE_BF, ONE_BF};

    // Q frags (phase-1 B-operand, B[k=ch][n=q], quads 1-3 ZERO: this is
    // what makes unmasked kf safe -- 0 * finite = 0 for k>=8).
    bf16x8 qf[4];
    #pragma unroll
    for (int qt = 0; qt < 4; ++qt) {
        qf[qt] = z8;
        if (qd == 0)
            qf[qt] = *(const bf16x8*)(Qh + ((size_t)b * N_ + i0 + qt * 16 + l16) * 8);
    }

    // K rows for this wave's jt-half only; X rows for its channel half.
    const unsigned short* Kp = Kh + ((size_t)b * N_ + p * 1024 + h * 16) * 8;
    const unsigned short* Xp = Xb + ((size_t)b * C_ + h * 32) * N_ + p * 1024;

    f32x4 acc[2][4];   // [ct][qt]: O'(c=h*32+ct*16+qd*4+r, q=qt*16+l16)
    #pragma unroll
    for (int ct = 0; ct < 2; ++ct)
        #pragma unroll
        for (int qt = 0; qt < 4; ++qt) acc[ct][qt] = zf;
    f32x4 acc_d[4];    // ones-row GEMM partials; wave handles qt where
    #pragma unroll     // (qt>>1)==h -- 2 MFMA/step each (balanced).
    for (int qt = 0; qt < 4; ++qt) acc_d[qt] = zf;

    // P addressing (v4-proven XOR swizzle); this wave writes its jt=h rows.
    const int swz   = (l16 & 3) << 2;
    const int pbase = p * 8192 + l16 * 64;
    const int woff  = ((h * 8 + qd * 2) ^ swz) << 2;
    const int roff  = ((qd * 4) ^ swz) << 2;

    // preload step 0 (kf UNMASKED: valid finite Kh memory; k>=8 products
    // hit qf zeros)
    bf16x8 kf[2], xf[2][2];
    kf[0] = *(const bf16x8*)(Kp + (size_t)l16 * 8);
    #pragma unroll
    for (int ct = 0; ct < 2; ++ct)
        xf[0][ct] = *(const bf16x8*)(Xp + (size_t)(ct * 16 + l16) * N_ + qd * 8);

    #pragma unroll 2
    for (int s = 0; s < 32; ++s) {
        const int cur = s & 1, nxt = cur ^ 1;
        const int jb = s * 32;
        char* pb_ = smem + pbase + cur * 4096;

        // phase 1: S^T[j][q] for jt=h (rows j=jb+h*16+qd*4+r, col q=l16)
        f32x4 sf[4];
        #pragma unroll
        for (int qt = 0; qt < 4; ++qt)
            sf[qt] = __builtin_amdgcn_mfma_f32_16x16x32_bf16(kf[cur], qf[qt], zf, 0, 0, 0);

        // prefetch next step's K and X frags (vmcnt not drained at the
        // barrier -- latency hides under next step's p1/exp2)
        if (s < 31) {
            kf[nxt] = *(const bf16x8*)(Kp + (size_t)(jb + 32 + l16) * 8);
            #pragma unroll
            for (int ct = 0; ct < 2; ++ct)
                xf[nxt][ct] = *(const bf16x8*)(Xp + (size_t)(ct * 16 + l16) * N_ + jb + 32 + qd * 8);
        }

        // exp2 -> pack this wave's jt-half into the pair P buffer
        #pragma unroll
        for (int qt = 0; qt < 4; ++qt) {
            float e0 = EXP2(sf[qt][0]);
            float e1 = EXP2(sf[qt][1]);
            float e2 = EXP2(sf[qt][2]);
            float e3 = EXP2(sf[qt][3]);
            uint2 u;
            u.x = pack_rtz(e0, e1);
            u.y = pack_rtz(e2, e3);
            *(uint2*)(pb_ + qt * 1024 + woff) = u;
        }

        // pair handshake without vmcnt drain (v14-proven): lgkmcnt(0)
        // drains this wave's ds_writes + step s-1 ds_reads; s_barrier
        // makes it block-wide. Prefetch global loads stay in flight.
        asm volatile("s_waitcnt lgkmcnt(0)" ::: "memory");
        __builtin_amdgcn_s_barrier();

        // phase 2: O'(half h) += X . P^T; d += 1 . P^T balanced:
        // wave h handles qt where (qt>>1)==h (2 ones-MFMA each).
        __builtin_amdgcn_s_setprio(1);
        #pragma unroll
        for (int qt = 0; qt < 4; ++qt) {
            bf16x8 pbf = *(const bf16x8*)(pb_ + qt * 1024 + roff);
            if ((qt >> 1) == h)
                acc_d[qt] = __builtin_amdgcn_mfma_f32_16x16x32_bf16(ones, pbf, acc_d[qt], 0, 0, 0);
            #pragma unroll
            for (int ct = 0; ct < 2; ++ct)
                acc[ct][qt] = __builtin_amdgcn_mfma_f32_16x16x32_bf16(xf[cur][ct], pbf, acc[ct][qt], 0, 0, 0);
        }
        __builtin_amdgcn_s_setprio(0);
    }

    // ---- denominator partials -> Dn[p][64]; h splits columns:
    //      h==0 writes qt{0,1} (cols 0-31), h==1 writes qt{2,3}. ----
    if (qd == 0) {
        #pragma unroll
        for (int qt = 0; qt < 4; ++qt)
            if ((qt >> 1) == h)
                *(float*)(smem + 65536 + (p * 64 + qt * 16 + l16) * 4) = acc_d[qt][0];
    }

    // ---- cross-wave O' reduce: halves reduce independently ----
    __syncthreads();                                   // S1: loop LDS done
    if (p != 0) {                                      // 6 dumpers, 8KB each
        const int slot = h * 3 + (p - 1);
        char* rb = smem + slot * 8192;
        #pragma unroll
        for (int ct = 0; ct < 2; ++ct)
            #pragma unroll
            for (int qt = 0; qt < 4; ++qt)
                *(f32x4*)(rb + (ct * 4 + qt) * 1024 + lane * 16) = acc[ct][qt];
    }
    __syncthreads();                                   // S2
    if (p == 0) {                                      // w0 (ct01), w4 (ct23)
        #pragma unroll
        for (int rr = 0; rr < 3; ++rr) {
            const char* rb = smem + (h * 3 + rr) * 8192;
            #pragma unroll
            for (int ct = 0; ct < 2; ++ct)
                #pragma unroll
                for (int qt = 0; qt < 4; ++qt)
                    acc[ct][qt] += *(const f32x4*)(rb + (ct * 4 + qt) * 1024 + lane * 16);
        }
        float* Or = (float*)(smem + 49152);
        #pragma unroll
        for (int ct = 0; ct < 2; ++ct)
            #pragma unroll
            for (int qt = 0; qt < 4; ++qt)
                #pragma unroll
                for (int r = 0; r < 4; ++r)
                    Or[(h * 32 + ct * 16 + qd * 4 + r) * 64 + qt * 16 + l16] = acc[ct][qt][r];
    }
    __syncthreads();                                   // S3: dump reads done
    {   // stage Wv fp32 -> [0,16K)
        float* Wvs = (float*)smem;
        for (int i = t; i < 4096; i += 512) Wvs[i] = wv[i];
    }
    __syncthreads();                                   // S4

    // ---- epilogue: out = Wv.O'/d + bv, fp32, all 8 waves ----
    const int q = t & 63, grp = t >> 6;                // grp = wave = c-group
    const float* Wvs = (const float*)smem;
    const float* Or  = (const float*)(smem + 49152);
    const float* Dn  = (const float*)(smem + 65536);
    float dtot = 0.f;
    #pragma unroll
    for (int r = 0; r < 4; ++r) dtot += Dn[r * 64 + q];
    const float inv = 1.0f / dtot;
    float o[8];
    #pragma unroll
    for (int r = 0; r < 8; ++r) o[r] = 0.f;
    for (int k = 0; k < 64; ++k) {
        float ov = Or[k * 64 + q];                      // lanes consecutive q
        #pragma unroll
        for (int r = 0; r < 8; ++r)
            o[r] += Wvs[(grp * 8 + r) * 64 + k] * ov;   // broadcast
    }
    #pragma unroll
    for (int r = 0; r < 8; ++r)
        out[((size_t)b * C_ + grp * 8 + r) * N_ + i0 + q] = o[r] * inv + bv[grp * 8 + r];
}

// ---------------------------------------------------------------------------
// Fallback (workspace too small): round-1 fused fp32 flash kernel (verified).
// ---------------------------------------------------------------------------
__global__ __launch_bounds__(256) void attn_fused_fallback(
    const float* __restrict__ x,
    const float* __restrict__ wq, const float* __restrict__ bq,
    const float* __restrict__ wk, const float* __restrict__ bk,
    const float* __restrict__ wv, const float* __restrict__ bv,
    float* __restrict__ out)
{
    __shared__ float Qs[64][8];
    __shared__ float Ks[8][64];
    __shared__ float Vs[64][C_];
    __shared__ float Ws[64][64 + 1];
    __shared__ float Xs[C_ * 64];
    __shared__ float Wks[8][C_];
    __shared__ float Wvs[C_][C_ + 1];

    const int t     = threadIdx.x;
    const int b     = blockIdx.x / (N_ / 64);
    const int i0    = (blockIdx.x % (N_ / 64)) * 64;
    const int jlane = t & 63;
    const int wgrp  = t >> 6;

    for (int l = t; l < 8 * C_;  l += 256) Wks[l >> 6][l & 63] = wk[l];
    for (int l = t; l < C_ * C_; l += 256) Wvs[l >> 6][l & 63] = wv[l];
    for (int l = t; l < C_ * 64; l += 256)
        Xs[(l >> 6) * 64 + (l & 63)] = x[((size_t)b * C_ + (l >> 6)) * N_ + i0 + (l & 63)];
    __syncthreads();
    {
        int qi = jlane;
        #pragma unroll
        for (int r = 0; r < 2; ++r) {
            int cc = wgrp * 2 + r;
            float a = bq[cc];
            for (int c = 0; c < C_; ++c) a += wq[cc * C_ + c] * Xs[c * 64 + qi];
            Qs[qi][cc] = a;
        }
    }
    __syncthreads();

    const int qi2 = t >> 2;
    const int cb  = (t & 3) << 4;
    float accv[16];
    #pragma unroll
    for (int r = 0; r < 16; ++r) accv[r] = 0.f;
    float denom = 0.f;

    for (int j0 = 0; j0 < N_; j0 += 64) {
        for (int l = t; l < C_ * 64; l += 256)
            Xs[(l >> 6) * 64 + (l & 63)] = x[((size_t)b * C_ + (l >> 6)) * N_ + j0 + (l & 63)];
        __syncthreads();
        {
            int j = jlane;
            #pragma unroll
            for (int r = 0; r < 2; ++r) {
                int cc = wgrp * 2 + r;
                float a = bk[cc];
                for (int c = 0; c < C_; ++c) a += Wks[cc][c] * Xs[c * 64 + j];
                Ks[cc][j] = a;
            }
        }
        {
            int vc = jlane;
            #pragma unroll 2
            for (int r = 0; r < 16; ++r) {
                int j = wgrp * 16 + r;
                float a = bv[vc];
                for (int c = 0; c < C_; ++c) a += Wvs[vc][c] * Xs[c * 64 + j];
                Vs[j][vc] = a;
            }
        }
        __syncthreads();
        {
            float kreg[8];
            #pragma unroll
            for (int cc = 0; cc < 8; ++cc) kreg[cc] = Ks[cc][jlane];
            #pragma unroll 4
            for (int r = 0; r < 16; ++r) {
                int qi = wgrp * 16 + r;
                float e = 0.f;
                #pragma unroll
                for (int cc = 0; cc < 8; ++cc) e += Qs[qi][cc] * kreg[cc];
                Ws[qi][jlane] = __expf(e);
            }
        }
        __syncthreads();
        #pragma unroll 4
        for (int j = 0; j < 64; ++j) {
            float wv2 = Ws[qi2][j];
            denom += wv2;
            const float4* vrow = (const float4*)(&Vs[j][cb]);
            float4 v0 = vrow[0], v1 = vrow[1], v2 = vrow[2], v3 = vrow[3];
            accv[0]  += wv2 * v0.x; accv[1]  += wv2 * v0.y; accv[2]  += wv2 * v0.z; accv[3]  += wv2 * v0.w;
            accv[4]  += wv2 * v1.x; accv[5]  += wv2 * v1.y; accv[6]  += wv2 * v1.z; accv[7]  += wv2 * v1.w;
            accv[8]  += wv2 * v2.x; accv[9]  += wv2 * v2.y; accv[10] += wv2 * v2.z; accv[11] += wv2 * v2.w;
            accv[12] += wv2 * v3.x; accv[13] += wv2 * v3.y; accv[14] += wv2 * v3.z; accv[15] += wv2 * v3.w;
        }
        __syncthreads();
    }

    const float inv = 1.0f / denom;
    #pragma unroll
    for (int r = 0; r < 16; ++r)
        out[((size_t)b * C_ + cb + r) * N_ + i0 + qi2] = accv[r] * inv;
}

// ---------------------------------------------------------------------------
extern "C" void kernel_launch(void* const* d_in, const int* in_sizes, int n_in,
                              void* d_out, int out_size, void* d_ws, size_t ws_size,
                              hipStream_t stream)
{
    const float* x  = (const float*)d_in[0];
    const float* wq = (const float*)d_in[1];
    const float* bq = (const float*)d_in[2];
    const float* wk = (const float*)d_in[3];
    const float* bk = (const float*)d_in[4];
    const float* wv = (const float*)d_in[5];
    const float* bv = (const float*)d_in[6];
    float* out = (float*)d_out;

    const size_t nQ = (size_t)B_ * N_ * 8;        // 256K elems
    const size_t nX = (size_t)B_ * C_ * N_;       // 2M elems
    const size_t needed = (2 * nQ + nX) * sizeof(unsigned short);   // 5 MB

    if (ws_size >= needed) {
        unsigned short* Qh = (unsigned short*)d_ws;
        unsigned short* Kh = Qh + nQ;
        unsigned short* Xb = Kh + nQ;
        prep_kernel<<<B_ * (N_ / 64), 256, 0, stream>>>(x, wq, bq, wk, bk, Qh, Kh, Xb);
        attn_mfma17_kernel<<<B_ * (N_ / 64), 512, 0, stream>>>(Qh, Kh, Xb, wv, bv, out);
    } else {
        attn_fused_fallback<<<B_ * (N_ / 64), 256, 0, stream>>>(x, wq, bq, wk, bk, wv, bv, out);
    }
}